// Round 7
// baseline (114.138 us; speedup 1.0000x reference)
//
#include <hip/hip_runtime.h>

// Problem constants (fixed by the reference):
//   B=4096, L=200, EMBEDDING_DIM=100, C=2 chunks of M=50, VOCAB=100000
constexpr int C_ = 2;
constexpr int M_ = 50;
constexpr int ED = 100;
constexpr float EPS = 1e-8f;

// clang native vectors: __builtin_nontemporal_load requires these (HIP's
// float4/float2 are class types it rejects).
typedef float vf4 __attribute__((ext_vector_type(4)));
typedef float vf2 __attribute__((ext_vector_type(2)));

// tbl layout per row: (a0, a0*dw0, a1, a1*dw1)

// ---------------------------------------------------------------------------
// Pass 1: per-vocab-row statistics. 256 threads = 4 waves per block; wave w
// handles chunk (w&1) of rows [block*128 + (w>>1)*64, +64). Chunk id is
// wave-uniform -> no divergence on the alignment branch. Each thread:
// 12 x float4 + 1 x float2 (chunk1: float2 at byte 200 then float4s from 208,
// both aligned). emb is read exactly once -> nontemporal to keep it out of
// the caches that tbl/idx want.
// ---------------------------------------------------------------------------
__global__ __launch_bounds__(256) void row_stats_kernel(
    const float* __restrict__ emb,   // [VOCAB, 100]
    const float* __restrict__ wgt,   // [100]
    const float* __restrict__ att,   // [100] = [2,50]
    float*       __restrict__ tbl,   // [VOCAB * 4]
    int vocab)
{
    __shared__ float2 s_uw[ED];   // (attend_u[e], weights[e])
    __shared__ float  s_su[C_];   // 1 / max(||u_c||, eps)

    const int t = threadIdx.x;
    if (t < ED) s_uw[t] = make_float2(att[t], wgt[t]);
    __syncthreads();
    if (t < C_) {
        float ss = 0.f;
        #pragma unroll
        for (int m = 0; m < M_; ++m) { float v = s_uw[t * M_ + m].x; ss += v * v; }
        s_su[t] = 1.0f / fmaxf(sqrtf(ss), EPS);
    }
    __syncthreads();

    const int w    = t >> 6;                  // wave id 0..3
    const int c    = w & 1;                   // wave-uniform chunk id
    const int lane = t & 63;
    const int r    = blockIdx.x * 128 + (w >> 1) * 64 + lane;
    if (r >= vocab) return;

    const float* rowp = emb + (long long)r * ED + c * M_;  // 50 floats
    float x[M_];
    if (c == 0) {
        // bytes [0,192) as 12 float4, [192,200) as float2 -- all aligned
        #pragma unroll
        for (int j = 0; j < 12; ++j) {
            const vf4 v = __builtin_nontemporal_load(reinterpret_cast<const vf4*>(rowp) + j);
            x[4*j] = v.x; x[4*j+1] = v.y; x[4*j+2] = v.z; x[4*j+3] = v.w;
        }
        const vf2 v = __builtin_nontemporal_load(reinterpret_cast<const vf2*>(rowp + 48));
        x[48] = v.x; x[49] = v.y;
    } else {
        // bytes [200,208) as float2, [208,400) as 12 float4 (208 % 16 == 0)
        const vf2 v = __builtin_nontemporal_load(reinterpret_cast<const vf2*>(rowp));
        x[0] = v.x; x[1] = v.y;
        #pragma unroll
        for (int j = 0; j < 12; ++j) {
            const vf4 u = __builtin_nontemporal_load(reinterpret_cast<const vf4*>(rowp + 2) + j);
            x[2+4*j] = u.x; x[3+4*j] = u.y; x[4+4*j] = u.z; x[5+4*j] = u.w;
        }
    }

    float sq = 0.f, du = 0.f, dw = 0.f;
    #pragma unroll
    for (int e = 0; e < M_; ++e) {
        const float2 uw = s_uw[c * M_ + e];   // wave-uniform broadcast: free
        sq = fmaf(x[e], x[e], sq);
        du = fmaf(x[e], uw.x, du);
        dw = fmaf(x[e], uw.y, dw);
    }
    const float cosv = du / fmaxf(sqrtf(sq), EPS) * s_su[c];
    const float a    = __expf(cosv);
    // wave writes its (a, a*dw) half of tbl[r] = (a0, a0*dw0, a1, a1*dw1)
    *reinterpret_cast<float2*>(tbl + 4 * r + 2 * c) = make_float2(a, a * dw);
}

// ---------------------------------------------------------------------------
// Pass 2: one WAVE per batch element. out[b] = P0/A0 + P1/A1 over L gathered
// table entries (16 B each, 1.6 MB table is L2/L3-resident). idx is
// read-once -> nontemporal; tbl gathers stay cached.
// ---------------------------------------------------------------------------
__global__ __launch_bounds__(256) void attend_kernel(
    const int*    __restrict__ idx,  // [B, L]
    const float4* __restrict__ tbl,  // [VOCAB] as (a0, ap0, a1, ap1)
    float*        __restrict__ out,  // [B]
    int B, int L)
{
    const int wave = threadIdx.x >> 6;
    const int lane = threadIdx.x & 63;
    const int b    = blockIdx.x * 4 + wave;
    if (b >= B) return;

    const int* ib = idx + (long long)b * L;
    float a0 = 0.f, a1 = 0.f, ap0 = 0.f, ap1 = 0.f;
    #pragma unroll 4
    for (int l = lane; l < L; l += 64) {       // coalesced idx read, cached gather
        const int r = __builtin_nontemporal_load(ib + l);
        const float4 v = tbl[r];
        a0 += v.x; ap0 += v.y; a1 += v.z; ap1 += v.w;
    }

    #pragma unroll
    for (int off = 32; off > 0; off >>= 1) {
        a0  += __shfl_down(a0,  off, 64);
        a1  += __shfl_down(a1,  off, 64);
        ap0 += __shfl_down(ap0, off, 64);
        ap1 += __shfl_down(ap1, off, 64);
    }
    if (lane == 0) out[b] = ap0 / a0 + ap1 / a1;
}

extern "C" void kernel_launch(void* const* d_in, const int* in_sizes, int n_in,
                              void* d_out, int out_size, void* d_ws, size_t ws_size,
                              hipStream_t stream) {
    const int*   idx = (const int*)d_in[0];    // word_idxs [4096,200] int32
    const float* emb = (const float*)d_in[1];  // emb_table [100000,100] f32
    const float* wgt = (const float*)d_in[2];  // weights   [100,1] f32
    const float* att = (const float*)d_in[3];  // attend_u  [2,50] f32
    float* out = (float*)d_out;                // [4096] f32

    const int B     = out_size;                 // 4096
    const int L     = in_sizes[0] / B;          // 200
    const int vocab = in_sizes[1] / ED;         // 100000

    float* tbl = (float*)d_ws;                  // 100000 * 16 B = 1.6 MB scratch

    row_stats_kernel<<<(vocab + 127) / 128, 256, 0, stream>>>(emb, wgt, att, tbl, vocab);
    attend_kernel<<<(B + 3) / 4, 256, 0, stream>>>(idx, (const float4*)tbl, out, B, L);
}

// Round 8
// 95.691 us; speedup vs baseline: 1.1928x; 1.1928x over previous
//
#include <hip/hip_runtime.h>

// Problem constants (fixed by the reference):
//   B=4096, L=200, EMBEDDING_DIM=100, C=2 chunks of M=50, VOCAB=100000
constexpr int C_ = 2;
constexpr int M_ = 50;
constexpr int ED = 100;
constexpr float EPS = 1e-8f;

// tbl layout per row: (a0, a0*dw0, a1, a1*dw1)

// ---------------------------------------------------------------------------
// Pass 1: per-vocab-row statistics. 256 threads = 4 waves per block; wave w
// handles chunk (w&1) of rows [block*128 + (w>>1)*64, +64). Chunk id is
// wave-uniform -> no divergence on the alignment branch. Each thread:
// 12 x float4 + 1 x float2 (chunk1: float2 at byte 200 then float4s from 208,
// both aligned). NOTE: plain cached loads on emb — within a lane, 4
// consecutive float4 loads share a 64 B line and L1 absorbs that reuse;
// nontemporal here cost +21 us of refetched lines (R7 post-mortem).
// ---------------------------------------------------------------------------
__global__ __launch_bounds__(256) void row_stats_kernel(
    const float* __restrict__ emb,   // [VOCAB, 100]
    const float* __restrict__ wgt,   // [100]
    const float* __restrict__ att,   // [100] = [2,50]
    float*       __restrict__ tbl,   // [VOCAB * 4]
    int vocab)
{
    __shared__ float2 s_uw[ED];   // (attend_u[e], weights[e])
    __shared__ float  s_su[C_];   // 1 / max(||u_c||, eps)

    const int t = threadIdx.x;
    if (t < ED) s_uw[t] = make_float2(att[t], wgt[t]);
    __syncthreads();
    if (t < C_) {
        float ss = 0.f;
        #pragma unroll
        for (int m = 0; m < M_; ++m) { float v = s_uw[t * M_ + m].x; ss += v * v; }
        s_su[t] = 1.0f / fmaxf(sqrtf(ss), EPS);
    }
    __syncthreads();

    const int w    = t >> 6;                  // wave id 0..3
    const int c    = w & 1;                   // wave-uniform chunk id
    const int lane = t & 63;
    const int r    = blockIdx.x * 128 + (w >> 1) * 64 + lane;
    if (r >= vocab) return;

    const float* rowp = emb + (long long)r * ED + c * M_;  // 50 floats
    float x[M_];
    if (c == 0) {
        // bytes [0,192) as 12 float4, [192,200) as float2 -- all aligned
        #pragma unroll
        for (int j = 0; j < 12; ++j) {
            const float4 v = reinterpret_cast<const float4*>(rowp)[j];
            x[4*j] = v.x; x[4*j+1] = v.y; x[4*j+2] = v.z; x[4*j+3] = v.w;
        }
        const float2 v = *reinterpret_cast<const float2*>(rowp + 48);
        x[48] = v.x; x[49] = v.y;
    } else {
        // bytes [200,208) as float2, [208,400) as 12 float4 (208 % 16 == 0)
        const float2 v = *reinterpret_cast<const float2*>(rowp);
        x[0] = v.x; x[1] = v.y;
        #pragma unroll
        for (int j = 0; j < 12; ++j) {
            const float4 u = reinterpret_cast<const float4*>(rowp + 2)[j];
            x[2+4*j] = u.x; x[3+4*j] = u.y; x[4+4*j] = u.z; x[5+4*j] = u.w;
        }
    }

    float sq = 0.f, du = 0.f, dw = 0.f;
    #pragma unroll
    for (int e = 0; e < M_; ++e) {
        const float2 uw = s_uw[c * M_ + e];   // wave-uniform broadcast: free
        sq = fmaf(x[e], x[e], sq);
        du = fmaf(x[e], uw.x, du);
        dw = fmaf(x[e], uw.y, dw);
    }
    const float cosv = du / fmaxf(sqrtf(sq), EPS) * s_su[c];
    const float a    = __expf(cosv);
    // wave writes its (a, a*dw) half of tbl[r] = (a0, a0*dw0, a1, a1*dw1)
    *reinterpret_cast<float2*>(tbl + 4 * r + 2 * c) = make_float2(a, a * dw);
}

// ---------------------------------------------------------------------------
// Pass 2: one WAVE per batch element. out[b] = P0/A0 + P1/A1 over L gathered
// table entries (16 B each, 1.6 MB table is L2/L3-resident). idx lines are
// consumed by exactly one wave instruction (dense 4 B coalesced) -> nt is
// safe there and keeps the read-once stream out of L2.
// ---------------------------------------------------------------------------
__global__ __launch_bounds__(256) void attend_kernel(
    const int*    __restrict__ idx,  // [B, L]
    const float4* __restrict__ tbl,  // [VOCAB] as (a0, ap0, a1, ap1)
    float*        __restrict__ out,  // [B]
    int B, int L)
{
    const int wave = threadIdx.x >> 6;
    const int lane = threadIdx.x & 63;
    const int b    = blockIdx.x * 4 + wave;
    if (b >= B) return;

    const int* ib = idx + (long long)b * L;
    float a0 = 0.f, a1 = 0.f, ap0 = 0.f, ap1 = 0.f;
    #pragma unroll 4
    for (int l = lane; l < L; l += 64) {       // coalesced idx read, cached gather
        const int r = __builtin_nontemporal_load(ib + l);
        const float4 v = tbl[r];
        a0 += v.x; ap0 += v.y; a1 += v.z; ap1 += v.w;
    }

    #pragma unroll
    for (int off = 32; off > 0; off >>= 1) {
        a0  += __shfl_down(a0,  off, 64);
        a1  += __shfl_down(a1,  off, 64);
        ap0 += __shfl_down(ap0, off, 64);
        ap1 += __shfl_down(ap1, off, 64);
    }
    if (lane == 0) out[b] = ap0 / a0 + ap1 / a1;
}

extern "C" void kernel_launch(void* const* d_in, const int* in_sizes, int n_in,
                              void* d_out, int out_size, void* d_ws, size_t ws_size,
                              hipStream_t stream) {
    const int*   idx = (const int*)d_in[0];    // word_idxs [4096,200] int32
    const float* emb = (const float*)d_in[1];  // emb_table [100000,100] f32
    const float* wgt = (const float*)d_in[2];  // weights   [100,1] f32
    const float* att = (const float*)d_in[3];  // attend_u  [2,50] f32
    float* out = (float*)d_out;                // [4096] f32

    const int B     = out_size;                 // 4096
    const int L     = in_sizes[0] / B;          // 200
    const int vocab = in_sizes[1] / ED;         // 100000

    float* tbl = (float*)d_ws;                  // 100000 * 16 B = 1.6 MB scratch

    row_stats_kernel<<<(vocab + 127) / 128, 256, 0, stream>>>(emb, wgt, att, tbl, vocab);
    attend_kernel<<<(B + 3) / 4, 256, 0, stream>>>(idx, (const float4*)tbl, out, B, L);
}

// Round 9
// 95.035 us; speedup vs baseline: 1.2010x; 1.0069x over previous
//
#include <hip/hip_runtime.h>

// Problem constants (fixed by the reference):
//   B=4096, L=200, EMBEDDING_DIM=100, C=2 chunks of M=50, VOCAB=100000
constexpr int C_ = 2;
constexpr int M_ = 50;
constexpr int ED = 100;
constexpr float EPS = 1e-8f;

// tbl layout per row: (a0, a0*dw0, a1, a1*dw1)
//
// Session-best configuration (R5, 93.3 us):
//  - Pass 1: 128-thread blocks, wave-uniform chunk mapping, 13 wide cached
//    loads per thread. Plain (cached) loads on emb: within a lane, 4
//    consecutive float4 loads share a 64 B line; L1 absorbs that reuse.
//    Nontemporal here cost +21 us of refetched lines (R7 post-mortem).
//  - Pass 2: one wave per batch element, plain loads (nt on idx was neutral
//    or slightly negative, R8 post-mortem).

// ---------------------------------------------------------------------------
// Pass 1: per-vocab-row statistics. alpha_c and alpha_c*proj_c depend ONLY on
// the vocab row (u, w are constants): tbl[r] = (a0, a0*dw0, a1, a1*dw1).
// Block = 128 threads = 2 waves; wave w handles chunk w of rows
// [blockIdx*64, +64). Chunk id is wave-uniform -> no divergence on the
// alignment branch. Each thread: 12 x float4 + 1 x float2 (chunk1: float2 at
// byte 200, float4s from byte 208; both aligned).
// ---------------------------------------------------------------------------
__global__ __launch_bounds__(128) void row_stats_kernel(
    const float* __restrict__ emb,   // [VOCAB, 100]
    const float* __restrict__ wgt,   // [100]
    const float* __restrict__ att,   // [100] = [2,50]
    float*       __restrict__ tbl,   // [VOCAB * 4]
    int vocab)
{
    __shared__ float2 s_uw[ED];   // (attend_u[e], weights[e])
    __shared__ float  s_su[C_];   // 1 / max(||u_c||, eps)

    const int t = threadIdx.x;
    if (t < ED) s_uw[t] = make_float2(att[t], wgt[t]);
    __syncthreads();
    if (t < C_) {
        float ss = 0.f;
        #pragma unroll
        for (int m = 0; m < M_; ++m) { float v = s_uw[t * M_ + m].x; ss += v * v; }
        s_su[t] = 1.0f / fmaxf(sqrtf(ss), EPS);
    }
    __syncthreads();

    const int c    = t >> 6;                  // wave-uniform chunk id (0 or 1)
    const int lane = t & 63;
    const int r    = blockIdx.x * 64 + lane;  // row
    if (r >= vocab) return;

    const float* rowp = emb + (long long)r * ED + c * M_;  // 50 floats
    float x[M_];
    if (c == 0) {
        // bytes [0,192) as 12 float4, [192,200) as float2 -- all aligned
        #pragma unroll
        for (int j = 0; j < 12; ++j) {
            const float4 v = reinterpret_cast<const float4*>(rowp)[j];
            x[4*j] = v.x; x[4*j+1] = v.y; x[4*j+2] = v.z; x[4*j+3] = v.w;
        }
        const float2 v = *reinterpret_cast<const float2*>(rowp + 48);
        x[48] = v.x; x[49] = v.y;
    } else {
        // bytes [200,208) as float2, [208,400) as 12 float4 (208 % 16 == 0)
        const float2 v = *reinterpret_cast<const float2*>(rowp);
        x[0] = v.x; x[1] = v.y;
        #pragma unroll
        for (int j = 0; j < 12; ++j) {
            const float4 u = reinterpret_cast<const float4*>(rowp + 2)[j];
            x[2+4*j] = u.x; x[3+4*j] = u.y; x[4+4*j] = u.z; x[5+4*j] = u.w;
        }
    }

    float sq = 0.f, du = 0.f, dw = 0.f;
    #pragma unroll
    for (int e = 0; e < M_; ++e) {
        const float2 uw = s_uw[c * M_ + e];   // wave-uniform broadcast: free
        sq = fmaf(x[e], x[e], sq);
        du = fmaf(x[e], uw.x, du);
        dw = fmaf(x[e], uw.y, dw);
    }
    const float cosv = du / fmaxf(sqrtf(sq), EPS) * s_su[c];
    const float a    = __expf(cosv);
    // wave writes its (a, a*dw) half of tbl[r] = (a0, a0*dw0, a1, a1*dw1)
    *reinterpret_cast<float2*>(tbl + 4 * r + 2 * c) = make_float2(a, a * dw);
}

// ---------------------------------------------------------------------------
// Pass 2: one WAVE per batch element. out[b] = P0/A0 + P1/A1 over L gathered
// table entries (16 B each; the 1.6 MB table is L2/L3-resident).
// No LDS, no __syncthreads.
// ---------------------------------------------------------------------------
__global__ __launch_bounds__(256) void attend_kernel(
    const int*    __restrict__ idx,  // [B, L]
    const float4* __restrict__ tbl,  // [VOCAB] as (a0, ap0, a1, ap1)
    float*        __restrict__ out,  // [B]
    int B, int L)
{
    const int wave = threadIdx.x >> 6;
    const int lane = threadIdx.x & 63;
    const int b    = blockIdx.x * 4 + wave;
    if (b >= B) return;

    const int* ib = idx + (long long)b * L;
    float a0 = 0.f, a1 = 0.f, ap0 = 0.f, ap1 = 0.f;
    #pragma unroll 4
    for (int l = lane; l < L; l += 64) {       // coalesced idx read, cached gather
        const float4 v = tbl[ib[l]];
        a0 += v.x; ap0 += v.y; a1 += v.z; ap1 += v.w;
    }

    #pragma unroll
    for (int off = 32; off > 0; off >>= 1) {
        a0  += __shfl_down(a0,  off, 64);
        a1  += __shfl_down(a1,  off, 64);
        ap0 += __shfl_down(ap0, off, 64);
        ap1 += __shfl_down(ap1, off, 64);
    }
    if (lane == 0) out[b] = ap0 / a0 + ap1 / a1;
}

extern "C" void kernel_launch(void* const* d_in, const int* in_sizes, int n_in,
                              void* d_out, int out_size, void* d_ws, size_t ws_size,
                              hipStream_t stream) {
    const int*   idx = (const int*)d_in[0];    // word_idxs [4096,200] int32
    const float* emb = (const float*)d_in[1];  // emb_table [100000,100] f32
    const float* wgt = (const float*)d_in[2];  // weights   [100,1] f32
    const float* att = (const float*)d_in[3];  // attend_u  [2,50] f32
    float* out = (float*)d_out;                // [4096] f32

    const int B     = out_size;                 // 4096
    const int L     = in_sizes[0] / B;          // 200
    const int vocab = in_sizes[1] / ED;         // 100000

    float* tbl = (float*)d_ws;                  // 100000 * 16 B = 1.6 MB scratch

    row_stats_kernel<<<(vocab + 63) / 64, 128, 0, stream>>>(emb, wgt, att, tbl, vocab);
    attend_kernel<<<(B + 3) / 4, 256, 0, stream>>>(idx, (const float4*)tbl, out, B, L);
}